// Round 6
// baseline (275.382 us; speedup 1.0000x reference)
//
#include <hip/hip_runtime.h>
#include <hip/hip_bf16.h>
#include <math.h>

// Problem constants (fixed by setup_inputs)
#define B_SZ 2
#define N_SEQ 2048
#define DIM 512
#define H_HEADS 8
#define D_HEAD 64
#define K_NN 32
#define M_DB 131072

typedef __attribute__((ext_vector_type(8))) short bf16x8;
typedef __attribute__((ext_vector_type(4))) float f32x4;

// async global->LDS, 16B per lane. LDS dest is wave-uniform base + lane*16;
// global src is per-lane (pre-swizzle the SOURCE, keep LDS linear).
#define GLL16(g, l)                                                       \
    __builtin_amdgcn_global_load_lds(                                     \
        (const __attribute__((address_space(1))) unsigned int*)(g),       \
        (__attribute__((address_space(3))) unsigned int*)(l), 16, 0, 0)

// ---------------------------------------------------------------------------
// fp32 -> (hi, lo) bf16 split. f ~= hi + lo to ~2^-17 relative.
// ---------------------------------------------------------------------------
__device__ __forceinline__ void cvt_hi_lo(float f, short& h, short& l) {
    unsigned u = __float_as_uint(f);
    unsigned uh = u + (0x7fffu + ((u >> 16) & 1u));
    h = (short)(uh >> 16);
    float r = f - __uint_as_float((uh >> 16) << 16);
    unsigned ur = __float_as_uint(r);
    l = (short)((ur + (0x7fffu + ((ur >> 16) & 1u))) >> 16);
}

__device__ __forceinline__ void split4(float4 a, ushort4& h, ushort4& l) {
    short hh, ll;
    cvt_hi_lo(a.x, hh, ll); h.x = hh; l.x = ll;
    cvt_hi_lo(a.y, hh, ll); h.y = hh; l.y = ll;
    cvt_hi_lo(a.z, hh, ll); h.z = hh; l.z = ll;
    cvt_hi_lo(a.w, hh, ll); h.w = hh; l.w = ll;
}

// ---------------------------------------------------------------------------
// Fused prep: split x (2048 blocks) + Wq/Wout (512 blocks) into bf16 hi/lo
// planes, and detect mask layout (1 block). One dispatch.
// ---------------------------------------------------------------------------
__global__ __launch_bounds__(256) void prep_kernel(
    const float4* __restrict__ x, const float4* __restrict__ wq,
    const float4* __restrict__ wout,
    ushort4* __restrict__ xhi, ushort4* __restrict__ xlo,
    ushort4* __restrict__ qhi, ushort4* __restrict__ qlo,
    ushort4* __restrict__ ohi, ushort4* __restrict__ olo,
    const unsigned char* __restrict__ mb, int* __restrict__ flag)
{
    const int bid = blockIdx.x;
    const int t = threadIdx.x;
    if (bid < 2048) {                       // x: 524288 float4s
        int i = bid * 256 + t;
        ushort4 h, l;
        split4(x[i], h, l);
        xhi[i] = h; xlo[i] = l;
    } else if (bid < 2560) {                // weights: 2*65536 float4s
        int i = (bid - 2048) * 256 + t;
        const int n4 = DIM * DIM / 4;       // 65536
        const float4* src = (i < n4) ? wq : wout;
        ushort4* dh = (i < n4) ? qhi : ohi;
        ushort4* dl = (i < n4) ? qlo : olo;
        int j = (i < n4) ? i : i - n4;
        ushort4 h, l;
        split4(src[j], h, l);
        dh[j] = h; dl[j] = l;
    } else {                                // mask-layout detect (64 lanes act)
        if (t < 64) {
            unsigned char v = 0;
            for (int e = t; e < 1024; e += 64) {
                v |= mb[4 * e + 1];
                v |= mb[4 * e + 2];
                v |= mb[4 * e + 3];
            }
            unsigned long long any = __ballot(v != 0);
            if (t == 0) *flag = (any != 0ull) ? 1 : 0;  // 1 = byte layout
        }
    }
}

// ---------------------------------------------------------------------------
// fp32-accurate MFMA GEMM (NT) on pre-split bf16 planes:
// C[m,n] = sum_k A[m,k]*W[n,k], 3 passes (hh + hl + lh) ~= fp32.
//
// Round-6 change: B (weights, 1MB total, L2-resident per XCD) is read
// DIRECTLY from global into registers with a one-step ping-pong prefetch —
// the round-5 kernel was LDS-read-pipe-bound (8 waves/CU x 8 ds_read_b128 x
// ~12cyc ~= 768 cyc/CU per kstep vs ~120 cyc of MFMA/SIMD). Only A is
// LDS-staged now: 3 x 8KB buffers, 2-deep prefetch, counted s_waitcnt
// vmcnt(2) (each iteration issues exactly 4 B-loads + 2 A-stages = 6 VMEM,
// so <=2 outstanding guarantees the A-stage for the current tile landed,
// under any intra-iteration issue order). Raw s_barrier, never a full
// drain in the main loop. B-register deps are covered by compiler waits.
// Per-wave per-kstep: 2 global_load_lds + 4 global_load + 4 ds_read + 12
// MFMA. Accumulation order identical to round-2/5 (absmax unchanged).
//
// A fragment-order staging (BK=32): chunk c(0..7): p=c>>2 (hi/lo plane),
// h=c&3 (16-row group). Wave w stages chunks w (hi) and w+4 (lo): lane l
// stages row m0+16w+(l&15), cols 8*(l>>4)..+7 of the 32-wide k-slice.
// Compute read = chunk*1024 + lane*16: linear, conflict-free.
//
// Block: 256 thr = 4 waves; wave = 32x32 out = 2x2 of 16x16x32 mfma.
// A-frag: m=lane&15, k=(lane>>4)*8+j.  C/D: col=lane&15, row=(lane>>4)*4+reg.
// ---------------------------------------------------------------------------
__global__ __launch_bounds__(256) void gemm_mfma_lds(
    const unsigned short* __restrict__ Ahi, const unsigned short* __restrict__ Alo,
    const unsigned short* __restrict__ Bhi, const unsigned short* __restrict__ Blo,
    float* __restrict__ C, int Mdim, int Ndim, int Kdim)
{
    __shared__ char lds[3][8192];
    const int t = threadIdx.x;
    const int w = t >> 6, lane = t & 63;
    const int r = lane & 15, qd = lane >> 4;
    const int wm = w & 1, wn = w >> 1;
    const int m0 = blockIdx.x * 64;
    const int n0 = blockIdx.y * 64;

    // A staging sources (kstep-0); wave w owns chunks w (hi) and w+4 (lo).
    const unsigned short* gA0;
    const unsigned short* gA1;
    {
        const int row = m0 + 16 * w + r;
        gA0 = Ahi + (size_t)row * Kdim + 8 * qd;
        gA1 = Alo + (size_t)row * Kdim + 8 * qd;
    }

    // B fragment sources, direct-from-global (L2-hot): [plane][ni].
    const unsigned short* gB[2][2];
#pragma unroll
    for (int p = 0; p < 2; ++p)
#pragma unroll
        for (int ni = 0; ni < 2; ++ni) {
            const int row = n0 + 32 * wn + 16 * ni + r;
            gB[p][ni] = (p ? Blo : Bhi) + (size_t)row * Kdim + 8 * qd;
        }

    f32x4 acc[2][2];
#pragma unroll
    for (int i = 0; i < 2; ++i)
#pragma unroll
        for (int j = 0; j < 2; ++j) acc[i][j] = (f32x4){0.f, 0.f, 0.f, 0.f};

    auto stage = [&](int buf, int kstep) {
        GLL16(gA0 + kstep * 32, &lds[buf][w * 1024]);
        GLL16(gA1 + kstep * 32, &lds[buf][(w + 4) * 1024]);
    };

    auto loadB = [&](bf16x8 (&B)[2][2], int kstep) {
#pragma unroll
        for (int p = 0; p < 2; ++p)
#pragma unroll
            for (int ni = 0; ni < 2; ++ni)
                B[p][ni] = *(const bf16x8*)(gB[p][ni] + kstep * 32);
    };

    auto compute = [&](int buf, const bf16x8 (&B8)[2][2]) {
        const char* base = lds[buf];
        bf16x8 A8[2][2];  // [plane][mi]
#pragma unroll
        for (int p = 0; p < 2; ++p)
#pragma unroll
            for (int i = 0; i < 2; ++i)
                A8[p][i] = *(const bf16x8*)(
                    base + (p * 4 + 2 * wm + i) * 1024 + lane * 16);
#pragma unroll
        for (int mi = 0; mi < 2; ++mi)
#pragma unroll
            for (int ni = 0; ni < 2; ++ni) {
                acc[mi][ni] = __builtin_amdgcn_mfma_f32_16x16x32_bf16(
                    A8[0][mi], B8[0][ni], acc[mi][ni], 0, 0, 0);
                acc[mi][ni] = __builtin_amdgcn_mfma_f32_16x16x32_bf16(
                    A8[0][mi], B8[1][ni], acc[mi][ni], 0, 0, 0);
                acc[mi][ni] = __builtin_amdgcn_mfma_f32_16x16x32_bf16(
                    A8[1][mi], B8[0][ni], acc[mi][ni], 0, 0, 0);
            }
    };

    const int nsteps = Kdim >> 5;  // 16
    bf16x8 Ba[2][2], Bb[2][2];     // static ping-pong (no runtime indexing)
    loadB(Ba, 0);                  // B(0) issued FIRST (oldest VMEM)
    stage(0, 0);
    stage(1, 1);
    int bc = 0;  // LDS buffer holding the current tile (runtime addr ok)
    for (int it = 0; it < nsteps / 2; ++it) {
        const int ks0 = 2 * it, ks1 = 2 * it + 1;
        // even step: compute(ks0) with Ba; prefetch B(ks0+1)->Bb, A(ks0+2)
        asm volatile("s_waitcnt vmcnt(2)" ::: "memory");
        __builtin_amdgcn_s_barrier();
        loadB(Bb, ks0 + 1 < nsteps ? ks0 + 1 : nsteps - 1);
        {
            int bs = bc + 2; if (bs >= 3) bs -= 3;
            stage(bs, ks0 + 2 < nsteps ? ks0 + 2 : nsteps - 1);
        }
        compute(bc, Ba);
        if (++bc == 3) bc = 0;
        // odd step: compute(ks1) with Bb; prefetch B(ks1+1)->Ba, A(ks1+2)
        asm volatile("s_waitcnt vmcnt(2)" ::: "memory");
        __builtin_amdgcn_s_barrier();
        loadB(Ba, ks1 + 1 < nsteps ? ks1 + 1 : nsteps - 1);
        {
            int bs = bc + 2; if (bs >= 3) bs -= 3;
            stage(bs, ks1 + 2 < nsteps ? ks1 + 2 : nsteps - 1);
        }
        compute(bc, Bb);
        if (++bc == 3) bc = 0;
    }

#pragma unroll
    for (int mi = 0; mi < 2; ++mi)
#pragma unroll
        for (int ni = 0; ni < 2; ++ni)
#pragma unroll
            for (int rr = 0; rr < 4; ++rr)
                C[(size_t)(m0 + 32 * wm + 16 * mi + qd * 4 + rr) * Ndim +
                  n0 + 32 * wn + 16 * ni + r] = acc[mi][ni][rr];
}

// ---------------------------------------------------------------------------
// Attention: one wave per (b,h,i) query. float4 gather: lane l = 16*grp+sub
// loads 16B of row (4g+grp); one wave-load fetches 4 rows (1KB).
//
// Row-0 redirect (round-3 counters: real-row-always doubled FETCH to 254MB
// and cost +18us — row 0 is cache-resident and serves ~50% of gathers for
// free; attn is bytes-bound at the ~3TB/s random-gather ceiling).
// Masked rows -> row 0; garbage annihilated by -FLT_MAX / zero weight;
// all-masked case uses real v addresses -> jax uniform 1/32. idx/mask loads
// issued BEFORE the q phase so their latency hides under q-norm. Output
// written as pre-split bf16 hi/lo planes.
// ---------------------------------------------------------------------------
__global__ __launch_bounds__(256) void attn_kernel(
    const float* __restrict__ qbuf,       // [b*n][512] fp32
    const float* __restrict__ mem_db,     // [b][M][128]
    const int* __restrict__ knn_idx,      // [b][h][n][K]
    const void* __restrict__ mem_mask,    // [b][h][n][K] bool-or-int32
    const float* __restrict__ scale_param,// [h]
    const int* __restrict__ flag,
    unsigned short* __restrict__ out_hi,  // [b*n][512] bf16 hi plane
    unsigned short* __restrict__ out_lo)  // [b*n][512] bf16 lo plane
{
    const int wave = blockIdx.x * 4 + (threadIdx.x >> 6);
    const int lane = threadIdx.x & 63;
    const int sub = lane & 15, grp = lane >> 4;
    const int i = wave % N_SEQ;
    const int bh = wave / N_SEQ;
    const int hi = bh % H_HEADS;
    const int bi = bh / H_HEADS;

    const int bytelayout = *flag;  // uniform

    // Issue index/mask loads first so they overlap the q phase.
    const size_t kb = ((size_t)(bi * H_HEADS + hi) * N_SEQ + i) * K_NN;
    int idxv = 0, maskv = 0;
    if (lane < K_NN) {
        idxv = knn_idx[kb + lane];
        if (bytelayout)
            maskv = ((const unsigned char*)mem_mask)[kb + lane] ? 1 : 0;
        else
            maskv = ((const int*)mem_mask)[kb + lane] ? 1 : 0;
    }

    const float* qrow = qbuf + (size_t)(bi * N_SEQ + i) * DIM + hi * D_HEAD;
    float qv = qrow[lane];
    float ss = qv * qv;
#pragma unroll
    for (int s = 32; s; s >>= 1) ss += __shfl_xor(ss, s);
    qv = qv / fmaxf(sqrtf(ss), 1e-12f);

    // q in float4-per-lane layout: q4[c] = q[4*sub + c]
    float q4[4];
#pragma unroll
    for (int c = 0; c < 4; ++c) q4[c] = __shfl(qv, 4 * sub + c);

    const float scale = __expf(scale_param[hi]);

    unsigned long long mbits = __ballot(maskv != 0);
    const bool allmasked = (mbits == 0ull);

    const float* dbb = mem_db + (size_t)bi * M_DB * (2 * D_HEAD);

    // Gather: group g covers rows 4g..4g+3; my row = 4g+grp, my 16B = [4*sub..]
    float4 kk[8], vv[8];
#pragma unroll
    for (int g = 0; g < 8; ++g) {
        int idx = __shfl(idxv, 4 * g + grp);
        bool mrow = (mbits >> (4 * g + grp)) & 1ull;
        size_t koff = mrow ? (size_t)idx * (2 * D_HEAD) : 0;
        size_t voff = (mrow || allmasked) ? (size_t)idx * (2 * D_HEAD) : 0;
        kk[g] = *(const float4*)(dbb + koff + 4 * sub);
        vv[g] = *(const float4*)(dbb + voff + D_HEAD + 4 * sub);
    }

    // Dot products: 4-elem partial per lane, 4-step butterfly over 16 lanes
    float s8[8];
#pragma unroll
    for (int g = 0; g < 8; ++g) {
        float p = q4[0] * kk[g].x + q4[1] * kk[g].y + q4[2] * kk[g].z + q4[3] * kk[g].w;
        p += __shfl_xor(p, 1);
        p += __shfl_xor(p, 2);
        p += __shfl_xor(p, 4);
        p += __shfl_xor(p, 8);
        s8[g] = p;  // full dot of row 4g+grp (replicated in 16-lane group)
    }

    // Collect: lane j<32 takes s8[j>>2] from source lane (j&3)<<4
    float simlane = -INFINITY;
#pragma unroll
    for (int g = 0; g < 8; ++g) {
        float tv = __shfl(s8[g], (lane & 3) << 4);
        if ((lane >> 2) == g) simlane = tv;  // lanes>=32 never match: stay -inf
    }
    if (lane < K_NN)
        simlane = maskv ? simlane * scale : -3.402823466e38f;

    // Softmax across 64 lanes
    float m = simlane;
#pragma unroll
    for (int s = 32; s; s >>= 1) m = fmaxf(m, __shfl_xor(m, s));
    float w = __expf(simlane - m);
    float l = w;
#pragma unroll
    for (int s = 32; s; s >>= 1) l += __shfl_xor(l, s);
    float winv = w / l;

    // Weighted sum of V (float4 layout), then reduce across the 4 groups
    float4 o = {0.f, 0.f, 0.f, 0.f};
#pragma unroll
    for (int g = 0; g < 8; ++g) {
        float wg = __shfl(winv, 4 * g + grp);
        o.x = fmaf(wg, vv[g].x, o.x);
        o.y = fmaf(wg, vv[g].y, o.y);
        o.z = fmaf(wg, vv[g].z, o.z);
        o.w = fmaf(wg, vv[g].w, o.w);
    }
#pragma unroll
    for (int s = 16; s <= 32; s <<= 1) {
        o.x += __shfl_xor(o.x, s);
        o.y += __shfl_xor(o.y, s);
        o.z += __shfl_xor(o.z, s);
        o.w += __shfl_xor(o.w, s);
    }
    if (grp == 0) {
        ushort4 h, l4;
        split4(o, h, l4);
        size_t off = ((size_t)(bi * N_SEQ + i) * DIM + hi * D_HEAD + 4 * sub) >> 2;
        ((ushort4*)out_hi)[off] = h;
        ((ushort4*)out_lo)[off] = l4;
    }
}

// ---------------------------------------------------------------------------
extern "C" void kernel_launch(void* const* d_in, const int* in_sizes, int n_in,
                              void* d_out, int out_size, void* d_ws, size_t ws_size,
                              hipStream_t stream) {
    const float* x        = (const float*)d_in[0];
    const float* mem_db   = (const float*)d_in[1];
    const int*   knn_idx  = (const int*)d_in[2];
    const void*  mem_mask = d_in[3];
    const float* Wq       = (const float*)d_in[4];
    // d_in[5] = Wkv: dead code in the reference, unused.
    const float* Wout     = (const float*)d_in[6];
    const float* scale_p  = (const float*)d_in[7];
    float* out = (float*)d_out;

    const int Mrows = B_SZ * N_SEQ;  // 4096
    const int n_x   = Mrows * DIM;   // 2097152
    const int n_w   = DIM * DIM;     // 262144

    // Workspace: flag | qbuf fp32 (8MB) | x planes (8MB) | ao planes (8MB)
    //            | 4 weight planes (2MB)   -> ~26.3 MB total
    char* ws = (char*)d_ws;
    int* flag = (int*)ws;
    float* qbuf = (float*)(ws + 256);
    unsigned short* x_hi  = (unsigned short*)(qbuf + (size_t)n_x);
    unsigned short* x_lo  = x_hi + n_x;
    unsigned short* ao_hi = x_lo + n_x;
    unsigned short* ao_lo = ao_hi + n_x;
    unsigned short* wq_hi = ao_lo + n_x;
    unsigned short* wq_lo = wq_hi + n_w;
    unsigned short* wo_hi = wq_lo + n_w;
    unsigned short* wo_lo = wo_hi + n_w;

    prep_kernel<<<2561, 256, 0, stream>>>(
        (const float4*)x, (const float4*)Wq, (const float4*)Wout,
        (ushort4*)x_hi, (ushort4*)x_lo,
        (ushort4*)wq_hi, (ushort4*)wq_lo, (ushort4*)wo_hi, (ushort4*)wo_lo,
        (const unsigned char*)mem_mask, flag);

    dim3 ggrid(Mrows / 64, DIM / 64);  // (64, 8) = 512 blocks = 2/CU
    gemm_mfma_lds<<<ggrid, 256, 0, stream>>>(x_hi, x_lo, wq_hi, wq_lo, qbuf,
                                             Mrows, DIM, DIM);

    const int n_waves = B_SZ * H_HEADS * N_SEQ;  // 32768
    attn_kernel<<<n_waves / 4, 256, 0, stream>>>(qbuf, mem_db, knn_idx, mem_mask,
                                                 scale_p, flag, ao_hi, ao_lo);

    gemm_mfma_lds<<<ggrid, 256, 0, stream>>>(ao_hi, ao_lo, wo_hi, wo_lo, out,
                                             Mrows, DIM, DIM);
}

// Round 7
// 262.415 us; speedup vs baseline: 1.0494x; 1.0494x over previous
//
#include <hip/hip_runtime.h>
#include <hip/hip_bf16.h>
#include <math.h>

// Problem constants (fixed by setup_inputs)
#define B_SZ 2
#define N_SEQ 2048
#define DIM 512
#define H_HEADS 8
#define D_HEAD 64
#define K_NN 32
#define M_DB 131072

typedef __attribute__((ext_vector_type(8))) short bf16x8;
typedef __attribute__((ext_vector_type(4))) float f32x4;

// async global->LDS, 16B per lane. LDS dest is wave-uniform base + lane*16;
// global src is per-lane (pre-swizzle the SOURCE, keep LDS linear).
#define GLL16(g, l)                                                       \
    __builtin_amdgcn_global_load_lds(                                     \
        (const __attribute__((address_space(1))) unsigned int*)(g),       \
        (__attribute__((address_space(3))) unsigned int*)(l), 16, 0, 0)

// ---------------------------------------------------------------------------
// fp32 -> (hi, lo) bf16 split. f ~= hi + lo to ~2^-17 relative.
// ---------------------------------------------------------------------------
__device__ __forceinline__ void cvt_hi_lo(float f, short& h, short& l) {
    unsigned u = __float_as_uint(f);
    unsigned uh = u + (0x7fffu + ((u >> 16) & 1u));
    h = (short)(uh >> 16);
    float r = f - __uint_as_float((uh >> 16) << 16);
    unsigned ur = __float_as_uint(r);
    l = (short)((ur + (0x7fffu + ((ur >> 16) & 1u))) >> 16);
}

__device__ __forceinline__ void split4(float4 a, ushort4& h, ushort4& l) {
    short hh, ll;
    cvt_hi_lo(a.x, hh, ll); h.x = hh; l.x = ll;
    cvt_hi_lo(a.y, hh, ll); h.y = hh; l.y = ll;
    cvt_hi_lo(a.z, hh, ll); h.z = hh; l.z = ll;
    cvt_hi_lo(a.w, hh, ll); h.w = hh; l.w = ll;
}

// ---------------------------------------------------------------------------
// Fused prep: split x (2048 blocks) + Wq/Wout (512 blocks) into bf16 hi/lo
// planes, and detect mask layout (1 block). One dispatch.
// ---------------------------------------------------------------------------
__global__ __launch_bounds__(256) void prep_kernel(
    const float4* __restrict__ x, const float4* __restrict__ wq,
    const float4* __restrict__ wout,
    ushort4* __restrict__ xhi, ushort4* __restrict__ xlo,
    ushort4* __restrict__ qhi, ushort4* __restrict__ qlo,
    ushort4* __restrict__ ohi, ushort4* __restrict__ olo,
    const unsigned char* __restrict__ mb, int* __restrict__ flag)
{
    const int bid = blockIdx.x;
    const int t = threadIdx.x;
    if (bid < 2048) {                       // x: 524288 float4s
        int i = bid * 256 + t;
        ushort4 h, l;
        split4(x[i], h, l);
        xhi[i] = h; xlo[i] = l;
    } else if (bid < 2560) {                // weights: 2*65536 float4s
        int i = (bid - 2048) * 256 + t;
        const int n4 = DIM * DIM / 4;       // 65536
        const float4* src = (i < n4) ? wq : wout;
        ushort4* dh = (i < n4) ? qhi : ohi;
        ushort4* dl = (i < n4) ? qlo : olo;
        int j = (i < n4) ? i : i - n4;
        ushort4 h, l;
        split4(src[j], h, l);
        dh[j] = h; dl[j] = l;
    } else {                                // mask-layout detect (64 lanes act)
        if (t < 64) {
            unsigned char v = 0;
            for (int e = t; e < 1024; e += 64) {
                v |= mb[4 * e + 1];
                v |= mb[4 * e + 2];
                v |= mb[4 * e + 3];
            }
            unsigned long long any = __ballot(v != 0);
            if (t == 0) *flag = (any != 0ull) ? 1 : 0;  // 1 = byte layout
        }
    }
}

// ---------------------------------------------------------------------------
// fp32-accurate MFMA GEMM (NT) on pre-split bf16 planes, LDS-STAGED with a
// 2-DEEP counted-vmcnt pipeline (round-5 version — best measured; round-6's
// B-from-global regressed by tripling VMEM issue and re-fetching B per wave):
// C[m,n] = sum_k A[m,k]*W[n,k], 3 passes (hh + hl + lh) ~= fp32.
//
// BK=32, THREE 16KB buffers, prefetch 2 tiles ahead, s_waitcnt vmcnt(4)
// (tile k's 4 stages are the oldest; tile k+1's may stay in flight), raw
// s_barrier (NOT __syncthreads, which drains vmcnt to 0).
// Per-wave per-kstep: 4 global_load_lds + 8 ds_read_b128 + 12 MFMA.
//
// Fragment-order staging: chunk c(0..7)=A: p=c>>2 (plane), h=c&3 (16-row
// group); c(8..15)=B likewise. Lane l stages row 16h+(l&15), cols
// 8*(l>>4)..+7 of the BK=32 slice. Compute read = chunk*1024 + lane*16:
// linear, conflict-free.
//
// Block: 256 thr = 4 waves; wave = 32x32 out = 2x2 of 16x16x32 mfma.
// A-frag: m=lane&15, k=(lane>>4)*8+j.  C/D: col=lane&15, row=(lane>>4)*4+reg.
// ---------------------------------------------------------------------------
__global__ __launch_bounds__(256) void gemm_mfma_lds(
    const unsigned short* __restrict__ Ahi, const unsigned short* __restrict__ Alo,
    const unsigned short* __restrict__ Bhi, const unsigned short* __restrict__ Blo,
    float* __restrict__ C, int Mdim, int Ndim, int Kdim)
{
    __shared__ char lds[3][16384];
    const int t = threadIdx.x;
    const int w = t >> 6, lane = t & 63;
    const int r = lane & 15, qd = lane >> 4;
    const int wm = w & 1, wn = w >> 1;
    const int m0 = blockIdx.x * 64;
    const int n0 = blockIdx.y * 64;

    // Per-wave staging sources: 4 chunks (cl = j*4 + w), kstep-0 addresses.
    const unsigned short* gsrc[4];
#pragma unroll
    for (int j = 0; j < 4; ++j) {
        const int cl = j * 4 + w;
        const int isB = cl >> 3;
        const int c = cl & 7;
        const int p = c >> 2, h = c & 3;
        const int row = (isB ? n0 : m0) + 16 * h + r;
        const unsigned short* plane =
            isB ? (p ? Blo : Bhi) : (p ? Alo : Ahi);
        gsrc[j] = plane + (size_t)row * Kdim + 8 * qd;
    }

    f32x4 acc[2][2];
#pragma unroll
    for (int i = 0; i < 2; ++i)
#pragma unroll
        for (int j = 0; j < 2; ++j) acc[i][j] = (f32x4){0.f, 0.f, 0.f, 0.f};

    auto stage = [&](int buf, int kstep) {
#pragma unroll
        for (int j = 0; j < 4; ++j) {
            const int cl = j * 4 + w;
            GLL16(gsrc[j] + kstep * 32, &lds[buf][cl * 1024]);
        }
    };

    auto compute = [&](int buf) {
        const char* base = lds[buf];
        bf16x8 A8[2][2], B8[2][2];  // [plane][i]
#pragma unroll
        for (int p = 0; p < 2; ++p)
#pragma unroll
            for (int i = 0; i < 2; ++i) {
                A8[p][i] = *(const bf16x8*)(
                    base + (p * 4 + 2 * wm + i) * 1024 + lane * 16);
                B8[p][i] = *(const bf16x8*)(
                    base + 8192 + (p * 4 + 2 * wn + i) * 1024 + lane * 16);
            }
#pragma unroll
        for (int mi = 0; mi < 2; ++mi)
#pragma unroll
            for (int ni = 0; ni < 2; ++ni) {
                acc[mi][ni] = __builtin_amdgcn_mfma_f32_16x16x32_bf16(
                    A8[0][mi], B8[0][ni], acc[mi][ni], 0, 0, 0);
                acc[mi][ni] = __builtin_amdgcn_mfma_f32_16x16x32_bf16(
                    A8[0][mi], B8[1][ni], acc[mi][ni], 0, 0, 0);
                acc[mi][ni] = __builtin_amdgcn_mfma_f32_16x16x32_bf16(
                    A8[1][mi], B8[0][ni], acc[mi][ni], 0, 0, 0);
            }
    };

    const int nsteps = Kdim >> 5;  // 16
    stage(0, 0);
    stage(1, 1);
    int bc = 0;  // buffer holding the current tile
    for (int ks = 0; ks < nsteps - 1; ++ks) {
        // tile ks done (its 4 loads are the oldest); tile ks+1's 4 may fly on
        asm volatile("s_waitcnt vmcnt(4)" ::: "memory");
        __builtin_amdgcn_s_barrier();
        if (ks + 2 < nsteps) {
            int bs = bc + 2; if (bs >= 3) bs -= 3;
            stage(bs, ks + 2);
        }
        compute(bc);
        if (++bc == 3) bc = 0;
    }
    asm volatile("s_waitcnt vmcnt(0)" ::: "memory");
    __builtin_amdgcn_s_barrier();
    compute(bc);

#pragma unroll
    for (int mi = 0; mi < 2; ++mi)
#pragma unroll
        for (int ni = 0; ni < 2; ++ni)
#pragma unroll
            for (int rr = 0; rr < 4; ++rr)
                C[(size_t)(m0 + 32 * wm + 16 * mi + qd * 4 + rr) * Ndim +
                  n0 + 32 * wn + 16 * ni + r] = acc[mi][ni][rr];
}

// ---------------------------------------------------------------------------
// Attention: one wave per (b,h,i) query. float4 gather: lane l = 16*grp+sub
// loads 16B of row (4g+grp); one wave-load fetches 4 rows (1KB).
//
// CHANGE: masked rows are SKIPPED via exec-mask predication instead of
// redirected to row 0. Disabled lanes issue no memory requests at all —
// removes ~50% of lane-requests (the old redirect's row-0 hits still
// consumed issue slots / L1 tag+return bandwidth). Numerics identical:
// masked lanes contribute 0-dot (logit overwritten with -FLT_MAX anyway)
// and 0-weighted zero V. All-masked wave loads real V rows -> uniform 1/32
// over real rows, matching the jax reference. idx/mask loads issued BEFORE
// the q phase so their latency hides under q-norm. Output written as
// pre-split bf16 hi/lo planes.
// ---------------------------------------------------------------------------
__global__ __launch_bounds__(256) void attn_kernel(
    const float* __restrict__ qbuf,       // [b*n][512] fp32
    const float* __restrict__ mem_db,     // [b][M][128]
    const int* __restrict__ knn_idx,      // [b][h][n][K]
    const void* __restrict__ mem_mask,    // [b][h][n][K] bool-or-int32
    const float* __restrict__ scale_param,// [h]
    const int* __restrict__ flag,
    unsigned short* __restrict__ out_hi,  // [b*n][512] bf16 hi plane
    unsigned short* __restrict__ out_lo)  // [b*n][512] bf16 lo plane
{
    const int wave = blockIdx.x * 4 + (threadIdx.x >> 6);
    const int lane = threadIdx.x & 63;
    const int sub = lane & 15, grp = lane >> 4;
    const int i = wave % N_SEQ;
    const int bh = wave / N_SEQ;
    const int hi = bh % H_HEADS;
    const int bi = bh / H_HEADS;

    const int bytelayout = *flag;  // uniform

    // Issue index/mask loads first so they overlap the q phase.
    const size_t kb = ((size_t)(bi * H_HEADS + hi) * N_SEQ + i) * K_NN;
    int idxv = 0, maskv = 0;
    if (lane < K_NN) {
        idxv = knn_idx[kb + lane];
        if (bytelayout)
            maskv = ((const unsigned char*)mem_mask)[kb + lane] ? 1 : 0;
        else
            maskv = ((const int*)mem_mask)[kb + lane] ? 1 : 0;
    }

    const float* qrow = qbuf + (size_t)(bi * N_SEQ + i) * DIM + hi * D_HEAD;
    float qv = qrow[lane];
    float ss = qv * qv;
#pragma unroll
    for (int s = 32; s; s >>= 1) ss += __shfl_xor(ss, s);
    qv = qv / fmaxf(sqrtf(ss), 1e-12f);

    // q in float4-per-lane layout: q4[c] = q[4*sub + c]
    float q4[4];
#pragma unroll
    for (int c = 0; c < 4; ++c) q4[c] = __shfl(qv, 4 * sub + c);

    const float scale = __expf(scale_param[hi]);

    unsigned long long mbits = __ballot(maskv != 0);
    const bool allmasked = (mbits == 0ull);

    const float* dbb = mem_db + (size_t)bi * M_DB * (2 * D_HEAD);

    // Gather: group g covers rows 4g..4g+3; my row = 4g+grp, my 16B = [4*sub..]
    // Masked rows: load skipped entirely (lane predicated off), kk/vv = 0.
    float4 kk[8], vv[8];
#pragma unroll
    for (int g = 0; g < 8; ++g) {
        int idx = __shfl(idxv, 4 * g + grp);
        bool need = ((mbits >> (4 * g + grp)) & 1ull) || allmasked;
        const float* rowp = dbb + (size_t)idx * (2 * D_HEAD) + 4 * sub;
        float4 k4 = {0.f, 0.f, 0.f, 0.f}, v4 = {0.f, 0.f, 0.f, 0.f};
        if (need) {
            k4 = *(const float4*)(rowp);
            v4 = *(const float4*)(rowp + D_HEAD);
        }
        kk[g] = k4; vv[g] = v4;
    }

    // Dot products: 4-elem partial per lane, 4-step butterfly over 16 lanes
    float s8[8];
#pragma unroll
    for (int g = 0; g < 8; ++g) {
        float p = q4[0] * kk[g].x + q4[1] * kk[g].y + q4[2] * kk[g].z + q4[3] * kk[g].w;
        p += __shfl_xor(p, 1);
        p += __shfl_xor(p, 2);
        p += __shfl_xor(p, 4);
        p += __shfl_xor(p, 8);
        s8[g] = p;  // full dot of row 4g+grp (replicated in 16-lane group)
    }

    // Collect: lane j<32 takes s8[j>>2] from source lane (j&3)<<4
    float simlane = -INFINITY;
#pragma unroll
    for (int g = 0; g < 8; ++g) {
        float tv = __shfl(s8[g], (lane & 3) << 4);
        if ((lane >> 2) == g) simlane = tv;  // lanes>=32 never match: stay -inf
    }
    if (lane < K_NN)
        simlane = maskv ? simlane * scale : -3.402823466e38f;

    // Softmax across 64 lanes
    float m = simlane;
#pragma unroll
    for (int s = 32; s; s >>= 1) m = fmaxf(m, __shfl_xor(m, s));
    float w = __expf(simlane - m);
    float l = w;
#pragma unroll
    for (int s = 32; s; s >>= 1) l += __shfl_xor(l, s);
    float winv = w / l;

    // Weighted sum of V (float4 layout), then reduce across the 4 groups
    float4 o = {0.f, 0.f, 0.f, 0.f};
#pragma unroll
    for (int g = 0; g < 8; ++g) {
        float wg = __shfl(winv, 4 * g + grp);
        o.x = fmaf(wg, vv[g].x, o.x);
        o.y = fmaf(wg, vv[g].y, o.y);
        o.z = fmaf(wg, vv[g].z, o.z);
        o.w = fmaf(wg, vv[g].w, o.w);
    }
#pragma unroll
    for (int s = 16; s <= 32; s <<= 1) {
        o.x += __shfl_xor(o.x, s);
        o.y += __shfl_xor(o.y, s);
        o.z += __shfl_xor(o.z, s);
        o.w += __shfl_xor(o.w, s);
    }
    if (grp == 0) {
        ushort4 h, l4;
        split4(o, h, l4);
        size_t off = ((size_t)(bi * N_SEQ + i) * DIM + hi * D_HEAD + 4 * sub) >> 2;
        ((ushort4*)out_hi)[off] = h;
        ((ushort4*)out_lo)[off] = l4;
    }
}

// ---------------------------------------------------------------------------
extern "C" void kernel_launch(void* const* d_in, const int* in_sizes, int n_in,
                              void* d_out, int out_size, void* d_ws, size_t ws_size,
                              hipStream_t stream) {
    const float* x        = (const float*)d_in[0];
    const float* mem_db   = (const float*)d_in[1];
    const int*   knn_idx  = (const int*)d_in[2];
    const void*  mem_mask = d_in[3];
    const float* Wq       = (const float*)d_in[4];
    // d_in[5] = Wkv: dead code in the reference, unused.
    const float* Wout     = (const float*)d_in[6];
    const float* scale_p  = (const float*)d_in[7];
    float* out = (float*)d_out;

    const int Mrows = B_SZ * N_SEQ;  // 4096
    const int n_x   = Mrows * DIM;   // 2097152
    const int n_w   = DIM * DIM;     // 262144

    // Workspace: flag | qbuf fp32 (8MB) | x planes (8MB) | ao planes (8MB)
    //            | 4 weight planes (2MB)   -> ~26.3 MB total
    char* ws = (char*)d_ws;
    int* flag = (int*)ws;
    float* qbuf = (float*)(ws + 256);
    unsigned short* x_hi  = (unsigned short*)(qbuf + (size_t)n_x);
    unsigned short* x_lo  = x_hi + n_x;
    unsigned short* ao_hi = x_lo + n_x;
    unsigned short* ao_lo = ao_hi + n_x;
    unsigned short* wq_hi = ao_lo + n_x;
    unsigned short* wq_lo = wq_hi + n_w;
    unsigned short* wo_hi = wq_lo + n_w;
    unsigned short* wo_lo = wo_hi + n_w;

    prep_kernel<<<2561, 256, 0, stream>>>(
        (const float4*)x, (const float4*)Wq, (const float4*)Wout,
        (ushort4*)x_hi, (ushort4*)x_lo,
        (ushort4*)wq_hi, (ushort4*)wq_lo, (ushort4*)wo_hi, (ushort4*)wo_lo,
        (const unsigned char*)mem_mask, flag);

    dim3 ggrid(Mrows / 64, DIM / 64);  // (64, 8) = 512 blocks = 2/CU
    gemm_mfma_lds<<<ggrid, 256, 0, stream>>>(x_hi, x_lo, wq_hi, wq_lo, qbuf,
                                             Mrows, DIM, DIM);

    const int n_waves = B_SZ * H_HEADS * N_SEQ;  // 32768
    attn_kernel<<<n_waves / 4, 256, 0, stream>>>(qbuf, mem_db, knn_idx, mem_mask,
                                                 scale_p, flag, ao_hi, ao_lo);

    gemm_mfma_lds<<<ggrid, 256, 0, stream>>>(ao_hi, ao_lo, wo_hi, wo_lo, out,
                                             Mrows, DIM, DIM);
}